// Round 13
// baseline (2766.770 us; speedup 1.0000x reference)
//
#include <hip/hip_runtime.h>
#include <hip/hip_bf16.h>
#include <stdint.h>

typedef __hip_bfloat16 bf16;
typedef __attribute__((ext_vector_type(8))) short short8;
typedef __attribute__((ext_vector_type(4))) float f32x4;
typedef __attribute__((ext_vector_type(4))) unsigned int u32x4;
typedef __attribute__((ext_vector_type(2))) unsigned int u32x2;

#define NN 65536
#define DD 512
#define EE 1048576
#define GG 128
#define LL 512

static __device__ __forceinline__ void gld_lds16(const void* g, void* l) {
  __builtin_amdgcn_global_load_lds((const __attribute__((address_space(1))) uint32_t*)g,
                                   (__attribute__((address_space(3))) uint32_t*)l, 16, 0, 0);
}

// ---------------- prep: transpose/cast weights to bf16 ----------------
__global__ __launch_bounds__(256) void k_prep(
    const float* __restrict__ Wc, const float* __restrict__ Wf1, const float* __restrict__ Wf2,
    const float* __restrict__ Wih, const float* __restrict__ Whh,
    bf16* __restrict__ WcT, bf16* __restrict__ Wf1T, bf16* __restrict__ Wf2T,
    bf16* __restrict__ WihB, bf16* __restrict__ WhhB)
{
  const int i = blockIdx.x * 256 + threadIdx.x;
  if (i < 512 * 512) {
    const int k = i >> 9, n = i & 511;
    WcT [n * 512 + k] = __float2bfloat16(Wc [i]);
    Wf1T[n * 512 + k] = __float2bfloat16(Wf1[i]);
    Wf2T[n * 512 + k] = __float2bfloat16(Wf2[i]);
  }
  if (i < 1536 * 512) {
    WihB[i] = __float2bfloat16(Wih[i]);
    WhhB[i] = __float2bfloat16(Whh[i]);
  }
}

// ---------------- cast node features to bf16 ----------------
__global__ __launch_bounds__(256) void k_cast(const float* __restrict__ f, bf16* __restrict__ o) {
  const long i = (long)(blockIdx.x * 256 + threadIdx.x) * 4;
  const float4 v = *(const float4*)&f[i];
  union { bf16 b[4]; ushort4 u; } pk;
  pk.b[0] = __float2bfloat16(v.x);
  pk.b[1] = __float2bfloat16(v.y);
  pk.b[2] = __float2bfloat16(v.z);
  pk.b[3] = __float2bfloat16(v.w);
  *(ushort4*)&o[i] = pk.u;
}

// ---------------- CSR build ----------------
__global__ __launch_bounds__(256) void k_deg(const int* __restrict__ dst, int* __restrict__ deg) {
  const int e = blockIdx.x * 256 + threadIdx.x;
  atomicAdd(&deg[dst[e]], 1);
}

__global__ __launch_bounds__(1024) void k_scan1(const int* __restrict__ deg,
                                                int* __restrict__ roff, int* __restrict__ partial) {
  __shared__ int sd[1024];
  const int t = threadIdx.x, b = blockIdx.x, i = b * 1024 + t;
  const int v = deg[i];
  sd[t] = v;
  __syncthreads();
  for (int off = 1; off < 1024; off <<= 1) {
    int add = (t >= off) ? sd[t - off] : 0;
    __syncthreads();
    sd[t] += add;
    __syncthreads();
  }
  roff[i] = sd[t] - v;
  if (t == 1023) partial[b] = sd[t];
}

__global__ __launch_bounds__(64) void k_scan2(const int* __restrict__ partial, int* __restrict__ base) {
  __shared__ int sd[64];
  const int t = threadIdx.x;
  const int v = partial[t];
  sd[t] = v;
  __syncthreads();
  for (int off = 1; off < 64; off <<= 1) {
    int add = (t >= off) ? sd[t - off] : 0;
    __syncthreads();
    sd[t] += add;
    __syncthreads();
  }
  base[t] = sd[t] - v;
  if (t == 63) base[64] = sd[63];
}

__global__ __launch_bounds__(1024) void k_scan3(const int* __restrict__ base,
                                                int* __restrict__ roff, int* __restrict__ cursor) {
  const int b = blockIdx.x, t = threadIdx.x, i = b * 1024 + t;
  const int v = roff[i] + base[b];
  roff[i] = v;
  cursor[i] = v;
  if (i == 0) roff[NN] = base[64];
}

__global__ __launch_bounds__(256) void k_fill(const int* __restrict__ src, const int* __restrict__ dst,
                                              int* __restrict__ cursor, int* __restrict__ csr) {
  const int e = blockIdx.x * 256 + threadIdx.x;
  const int p = atomicAdd(&cursor[dst[e]], 1);
  csr[p] = src[e];
}

// ---------------- mean aggregation (bf16 gather, fp32 accum, 4-wide ILP) ----------------
__global__ __launch_bounds__(128) void k_agg(
    const bf16* __restrict__ featsb, const int* __restrict__ csr,
    const int* __restrict__ roff, bf16* __restrict__ agg)
{
  const int n = blockIdx.x, t = threadIdx.x;
  const int s0 = roff[n], s1 = roff[n + 1];
  float a0 = 0.f, a1 = 0.f, a2 = 0.f, a3 = 0.f;
  int i = s0;
  for (; i + 4 <= s1; i += 4) {
    const int sA = csr[i], sB = csr[i + 1], sC = csr[i + 2], sD = csr[i + 3];
    const ushort4 vA = *(const ushort4*)&featsb[(long)sA * 512 + t * 4];
    const ushort4 vB = *(const ushort4*)&featsb[(long)sB * 512 + t * 4];
    const ushort4 vC = *(const ushort4*)&featsb[(long)sC * 512 + t * 4];
    const ushort4 vD = *(const ushort4*)&featsb[(long)sD * 512 + t * 4];
    union { uint32_t u; float f; } c;
    c.u = (uint32_t)vA.x << 16; a0 += c.f;  c.u = (uint32_t)vA.y << 16; a1 += c.f;
    c.u = (uint32_t)vA.z << 16; a2 += c.f;  c.u = (uint32_t)vA.w << 16; a3 += c.f;
    c.u = (uint32_t)vB.x << 16; a0 += c.f;  c.u = (uint32_t)vB.y << 16; a1 += c.f;
    c.u = (uint32_t)vB.z << 16; a2 += c.f;  c.u = (uint32_t)vB.w << 16; a3 += c.f;
    c.u = (uint32_t)vC.x << 16; a0 += c.f;  c.u = (uint32_t)vC.y << 16; a1 += c.f;
    c.u = (uint32_t)vC.z << 16; a2 += c.f;  c.u = (uint32_t)vC.w << 16; a3 += c.f;
    c.u = (uint32_t)vD.x << 16; a0 += c.f;  c.u = (uint32_t)vD.y << 16; a1 += c.f;
    c.u = (uint32_t)vD.z << 16; a2 += c.f;  c.u = (uint32_t)vD.w << 16; a3 += c.f;
  }
  for (; i < s1; ++i) {
    const int s = csr[i];
    const ushort4 v = *(const ushort4*)&featsb[(long)s * 512 + t * 4];
    union { uint32_t u; float f; } c;
    c.u = (uint32_t)v.x << 16; a0 += c.f;  c.u = (uint32_t)v.y << 16; a1 += c.f;
    c.u = (uint32_t)v.z << 16; a2 += c.f;  c.u = (uint32_t)v.w << 16; a3 += c.f;
  }
  const float sc = 1.f / fmaxf((float)(s1 - s0), 1.f);
  union { bf16 b[4]; ushort4 u; } pk;
  pk.b[0] = __float2bfloat16(a0 * sc);
  pk.b[1] = __float2bfloat16(a1 * sc);
  pk.b[2] = __float2bfloat16(a2 * sc);
  pk.b[3] = __float2bfloat16(a3 * sc);
  *(ushort4*)&agg[(long)n * 512 + t * 4] = pk.u;
}

// ---------------- bf16 GEMM: C[M,Ncols] = A[M,512] @ Bt[Ncols,512]^T + bias ----------------
template<bool GATHER, bool RELU>
__global__ __launch_bounds__(256) void k_gemm(
    const bf16* __restrict__ A, const bf16* __restrict__ Bt,
    const float* __restrict__ bias, const int* __restrict__ gidx,
    bf16* __restrict__ outb, int Ncols)
{
  __shared__ bf16 lsA[128 * 64];
  __shared__ bf16 lsB[128 * 64];
  const int t = threadIdx.x;
  const int lane = t & 63, wid = t >> 6;
  const int wr = wid >> 1, wc = wid & 1;
  const int tm = blockIdx.y * 128, tn = blockIdx.x * 128;
  const int col8 = (t & 7) * 8;
  const int rsub = t >> 3;
  const int lc = lane & 15, lk = lane >> 4;

  long arow[4], brow[4];
#pragma unroll
  for (int i = 0; i < 4; ++i) {
    const int r = tm + i * 32 + rsub;
    int ar = r;
    if constexpr (GATHER) ar = gidx[r];
    arow[i] = (long)ar * 512;
    brow[i] = (long)(tn + i * 32 + rsub) * 512;
  }

  f32x4 acc[4][4];
#pragma unroll
  for (int a = 0; a < 4; ++a)
#pragma unroll
    for (int b = 0; b < 4; ++b) acc[a][b] = (f32x4){0.f, 0.f, 0.f, 0.f};

  for (int ks = 0; ks < 8; ++ks) {
    const int k0 = ks * 64;
#pragma unroll
    for (int i = 0; i < 4; ++i) {
      gld_lds16(A  + arow[i] + k0 + col8, &lsA[i * 2048 + t * 8]);
      gld_lds16(Bt + brow[i] + k0 + col8, &lsB[i * 2048 + t * 8]);
    }
    __syncthreads();
#pragma unroll
    for (int kk = 0; kk < 2; ++kk) {
      short8 af[4], bfr[4];
#pragma unroll
      for (int mi = 0; mi < 4; ++mi)
        af[mi] = *(const short8*)&lsA[(wr * 64 + mi * 16 + lc) * 64 + kk * 32 + lk * 8];
#pragma unroll
      for (int ni = 0; ni < 4; ++ni)
        bfr[ni] = *(const short8*)&lsB[(wc * 64 + ni * 16 + lc) * 64 + kk * 32 + lk * 8];
#pragma unroll
      for (int mi = 0; mi < 4; ++mi)
#pragma unroll
        for (int ni = 0; ni < 4; ++ni)
          acc[mi][ni] = __builtin_amdgcn_mfma_f32_16x16x32_bf16(af[mi], bfr[ni], acc[mi][ni], 0, 0, 0);
    }
    __syncthreads();
  }

  float bv[4];
#pragma unroll
  for (int ni = 0; ni < 4; ++ni) bv[ni] = bias[tn + wc * 64 + ni * 16 + lc];

#pragma unroll
  for (int mi = 0; mi < 4; ++mi) {
    const int r0 = tm + wr * 64 + mi * 16 + lk * 4;
#pragma unroll
    for (int j = 0; j < 4; ++j) {
      const int row = r0 + j;
      const long orow = (long)row * Ncols;
#pragma unroll
      for (int ni = 0; ni < 4; ++ni) {
        float v = acc[mi][ni][j] + bv[ni];
        if constexpr (RELU) v = fmaxf(v, 0.f);
        const int c = tn + wc * 64 + ni * 16 + lc;
        outb[orow + c] = __float2bfloat16(v);
      }
    }
  }
}

// ---------------- ff2 GEMM reading ys2 layout, scatter output ----------------
// ys2 element (g,l,k):  byte = ((l*8 + (g>>4))*32 + (k>>4))*512 + (g&15)*32 + (k&15)*2
__global__ __launch_bounds__(256) void k_gemm_ys(
    const uint8_t* __restrict__ Ay, const bf16* __restrict__ Bt,
    const float* __restrict__ bias, const int* __restrict__ gidx,
    float* __restrict__ outf)
{
  __shared__ bf16 lsA[128 * 64];
  __shared__ bf16 lsB[128 * 64];
  const int t = threadIdx.x;
  const int lane = t & 63, wid = t >> 6;
  const int wr = wid >> 1, wc = wid & 1;
  const int tm = blockIdx.y * 128, tn = blockIdx.x * 128;
  const int col8 = (t & 7) * 8;
  const int rsub = t >> 3;
  const int lc = lane & 15, lk = lane >> 4;

  long arow[4], brow[4];
#pragma unroll
  for (int i = 0; i < 4; ++i) {
    const int r = tm + i * 32 + rsub;
    const int g = r >> 9, l = r & 511;
    arow[i] = ((long)l * 8 + (g >> 4)) * 16384 + (g & 15) * 32;
    brow[i] = (long)(tn + i * 32 + rsub) * 512;
  }

  f32x4 acc[4][4];
#pragma unroll
  for (int a = 0; a < 4; ++a)
#pragma unroll
    for (int b = 0; b < 4; ++b) acc[a][b] = (f32x4){0.f, 0.f, 0.f, 0.f};

  for (int ks = 0; ks < 8; ++ks) {
    const int k0 = ks * 64;
    const int kk16 = k0 + col8;
    const long aoff = ((long)(kk16 >> 4) << 9) + ((kk16 & 15) << 1);
#pragma unroll
    for (int i = 0; i < 4; ++i) {
      gld_lds16(Ay + arow[i] + aoff, &lsA[i * 2048 + t * 8]);
      gld_lds16(Bt + brow[i] + k0 + col8, &lsB[i * 2048 + t * 8]);
    }
    __syncthreads();
#pragma unroll
    for (int kk = 0; kk < 2; ++kk) {
      short8 af[4], bfr[4];
#pragma unroll
      for (int mi = 0; mi < 4; ++mi)
        af[mi] = *(const short8*)&lsA[(wr * 64 + mi * 16 + lc) * 64 + kk * 32 + lk * 8];
#pragma unroll
      for (int ni = 0; ni < 4; ++ni)
        bfr[ni] = *(const short8*)&lsB[(wc * 64 + ni * 16 + lc) * 64 + kk * 32 + lk * 8];
#pragma unroll
      for (int mi = 0; mi < 4; ++mi)
#pragma unroll
        for (int ni = 0; ni < 4; ++ni)
          acc[mi][ni] = __builtin_amdgcn_mfma_f32_16x16x32_bf16(af[mi], bfr[ni], acc[mi][ni], 0, 0, 0);
    }
    __syncthreads();
  }

  float bv[4];
#pragma unroll
  for (int ni = 0; ni < 4; ++ni) bv[ni] = bias[tn + wc * 64 + ni * 16 + lc];

#pragma unroll
  for (int mi = 0; mi < 4; ++mi) {
    const int r0 = tm + wr * 64 + mi * 16 + lk * 4;
#pragma unroll
    for (int j = 0; j < 4; ++j) {
      const int row = r0 + j;
      const long orow = (long)gidx[row] * 512;
#pragma unroll
      for (int ni = 0; ni < 4; ++ni) {
        const int c = tn + wc * 64 + ni * 16 + lc;
        outf[orow + c] = acc[mi][ni][j] + bv[ni];
      }
    }
  }
}

// ---------------- persistent GRU v13: 16 producers/chain (narrow barrier) ----------
// Protocol byte-identical to r12 (gi before poll; padded per-producer flag
// lines; sc0 sc1 h stores; vmcnt(0) drain; agent stamp; same ys2 byte layout
// -> consumer loads and k_gemm_ys unchanged). Geometry change only: 128
// blocks x 64 threads = 8 chains x 16 producers; each wave owns 32 d-cols
// via TWO MFMA tiles (rows cols0+lc and cols0+16+lc). Halving the barrier
// width (32->16 stamps) cuts the straggler-max tail the consumer gates on.
__global__ __launch_bounds__(64, 1) void k_gru13(
    const bf16* __restrict__ Whh, const float* __restrict__ bhh,
    const bf16* __restrict__ gi, uint8_t* __restrict__ ys2, int* __restrict__ flags)
{
  __shared__ bf16 lsW[96 * 520];
  const int t = threadIdx.x, lane = t & 63;
  const int chain = blockIdx.x >> 4, p = blockIdx.x & 15;   // producer 0..15
  const int lc = lane & 15, lk = lane >> 4;
  const int g0 = chain * 16;
  const int cols0 = p * 32;
  const int d0a = cols0 + lk * 4;          // tile A: 4 consecutive d (group lc)
  const int d0b = cols0 + 16 + lk * 4;     // tile B

  // stage W slice: rows gate*32+cc -> Whh[(gate<<9) + cols0 + cc], 96 rows x 512
  for (int it = 0; it < 96; ++it) {
    const int c = it * 64 + t;
    const int row = c >> 6, col8 = (c & 63) * 8;
    const int e = ((row >> 5) << 9) + cols0 + (row & 31);
    *(uint4*)&lsW[row * 520 + col8] = *(const uint4*)&Whh[(long)e * 512 + col8];
  }
  __syncthreads();

  float bRa[4], bZa[4], bNa[4], bRb[4], bZb[4], bNb[4];
#pragma unroll
  for (int j = 0; j < 4; ++j) {
    bRa[j] = bhh[d0a + j];  bZa[j] = bhh[512 + d0a + j];  bNa[j] = bhh[1024 + d0a + j];
    bRb[j] = bhh[d0b + j];  bZb[j] = bhh[512 + d0b + j];  bNb[j] = bhh[1024 + d0b + j];
  }
  float hregA[4] = {0.f, 0.f, 0.f, 0.f};
  float hregB[4] = {0.f, 0.f, 0.f, 0.f};

  // gi: group g0+lc; tile A gates at +0/+1024/+2048 B, tile B at +32 more
  const bf16* gp = gi + (long)(g0 + lc) * 786432 + d0a;
  // producer stores: tile A -> slab byte p*1024 + lc*32 + lk*8; tile B -> +512
  uint8_t* psto = ys2 + (long)chain * 16384 + p * 1024 + lc * 32 + lk * 8;
  // consumer lane offset (bytes) within a (l,chain) slab — r12 verbatim
  const long laneoff = (long)(lk >> 1) * 512 + lc * 32 + (lk & 1) * 16;

  int* chflags = flags + chain * 16 * 32;      // 16 producers x 128B stride
  int* myflag  = chflags + p * 32;

  for (int l = 0; l < 512; ++l) {
    // gi loads issued BEFORE the poll (r8/r12-proven: drain hides under spin)
    u32x2 gRa, gZa, gNa, gRb, gZb, gNb;
    asm volatile("global_load_dwordx2 %0, %1, off"             : "=v"(gRa) : "v"(gp) : "memory");
    asm volatile("global_load_dwordx2 %0, %1, off offset:1024" : "=v"(gZa) : "v"(gp) : "memory");
    asm volatile("global_load_dwordx2 %0, %1, off offset:2048" : "=v"(gNa) : "v"(gp) : "memory");
    asm volatile("global_load_dwordx2 %0, %1, off offset:32"   : "=v"(gRb) : "v"(gp) : "memory");
    asm volatile("global_load_dwordx2 %0, %1, off offset:1056" : "=v"(gZb) : "v"(gp) : "memory");
    asm volatile("global_load_dwordx2 %0, %1, off offset:2080" : "=v"(gNb) : "v"(gp) : "memory");
    gp += 1536;

    f32x4 accA[3] = { (f32x4){0.f,0.f,0.f,0.f}, (f32x4){0.f,0.f,0.f,0.f}, (f32x4){0.f,0.f,0.f,0.f} };
    f32x4 accB[3] = { (f32x4){0.f,0.f,0.f,0.f}, (f32x4){0.f,0.f,0.f,0.f}, (f32x4){0.f,0.f,0.f,0.f} };
    if (l > 0) {
      // wait for all 16 producers of this chain to stamp step l
      int ok;
      do {
        const int v = __hip_atomic_load(&chflags[(lane & 15) * 32], __ATOMIC_RELAXED,
                                        __HIP_MEMORY_SCOPE_AGENT);
        ok = __all(v >= l);
      } while (!ok);
      asm volatile("" ::: "memory");

      // h_{l-1} = ys2[l-1][chain]: 16 pipelined 16B loads = MFMA B-frags (r12 verbatim)
      const uint8_t* pb = ys2 + ((long)(l - 1) * 8 + chain) * 16384 + laneoff;
      u32x4 hv[16];
#pragma unroll
      for (int q = 0; q < 4; ++q) {
        const uint8_t* pbq = pb + q * 4096;
#pragma unroll
        for (int r2 = 0; r2 < 4; ++r2)
          asm volatile("global_load_dwordx4 %0, %1, off offset:%2 sc0 sc1"
                       : "=v"(hv[q * 4 + r2]) : "v"(pbq), "n"(r2 * 1024) : "memory");
      }
      asm volatile("s_waitcnt vmcnt(0)" ::: "memory");
      __builtin_amdgcn_sched_barrier(0);

#pragma unroll
      for (int kk = 0; kk < 16; ++kk) {
        union { u32x4 u; short8 s; } cv;
        cv.u = hv[kk];
#pragma unroll
        for (int gate = 0; gate < 3; ++gate) {
          const short8 wfA = *(const short8*)&lsW[(gate * 32 + lc) * 520 + kk * 32 + lk * 8];
          const short8 wfB = *(const short8*)&lsW[(gate * 32 + 16 + lc) * 520 + kk * 32 + lk * 8];
          accA[gate] = __builtin_amdgcn_mfma_f32_16x16x32_bf16(wfA, cv.s, accA[gate], 0, 0, 0);
          accB[gate] = __builtin_amdgcn_mfma_f32_16x16x32_bf16(wfB, cv.s, accB[gate], 0, 0, 0);
        }
      }
    } else {
      asm volatile("s_waitcnt vmcnt(0)" ::: "memory");
      __builtin_amdgcn_sched_barrier(0);
    }

    uint32_t hbA[4], hbB[4];
#pragma unroll
    for (int j = 0; j < 4; ++j) {
      const uint32_t sh = (j & 1) * 16;
      union { uint32_t u; float f; } cR, cZ, cN;
      cR.u = ((gRa[j >> 1] >> sh) & 0xffffu) << 16;
      cZ.u = ((gZa[j >> 1] >> sh) & 0xffffu) << 16;
      cN.u = ((gNa[j >> 1] >> sh) & 0xffffu) << 16;
      const float r = 1.f / (1.f + __expf(-(cR.f + accA[0][j] + bRa[j])));
      const float z = 1.f / (1.f + __expf(-(cZ.f + accA[1][j] + bZa[j])));
      const float x2 = cN.f + r * (accA[2][j] + bNa[j]);
      const float ex = __expf(2.f * x2);
      const float n = 1.f - 2.f / (ex + 1.f);
      const float hn = (1.f - z) * n + z * hregA[j];
      hregA[j] = hn;
      const bf16 hnb = __float2bfloat16(hn);
      hbA[j] = (uint32_t)(*(const uint16_t*)&hnb);
    }
#pragma unroll
    for (int j = 0; j < 4; ++j) {
      const uint32_t sh = (j & 1) * 16;
      union { uint32_t u; float f; } cR, cZ, cN;
      cR.u = ((gRb[j >> 1] >> sh) & 0xffffu) << 16;
      cZ.u = ((gZb[j >> 1] >> sh) & 0xffffu) << 16;
      cN.u = ((gNb[j >> 1] >> sh) & 0xffffu) << 16;
      const float r = 1.f / (1.f + __expf(-(cR.f + accB[0][j] + bRb[j])));
      const float z = 1.f / (1.f + __expf(-(cZ.f + accB[1][j] + bZb[j])));
      const float x2 = cN.f + r * (accB[2][j] + bNb[j]);
      const float ex = __expf(2.f * x2);
      const float n = 1.f - 2.f / (ex + 1.f);
      const float hn = (1.f - z) * n + z * hregB[j];
      hregB[j] = hn;
      const bf16 hnb = __float2bfloat16(hn);
      hbB[j] = (uint32_t)(*(const uint16_t*)&hnb);
    }
    u32x2 hpA, hpB;
    hpA[0] = hbA[0] | (hbA[1] << 16);  hpA[1] = hbA[2] | (hbA[3] << 16);
    hpB[0] = hbB[0] | (hbB[1] << 16);  hpB[1] = hbB[2] | (hbB[3] << 16);
    asm volatile("global_store_dwordx2 %0, %1, off sc0 sc1" :: "v"(psto),       "v"(hpA) : "memory");
    asm volatile("global_store_dwordx2 %0, %1, off offset:512 sc0 sc1" :: "v"(psto), "v"(hpB) : "memory");
    psto += 131072;                                     // next l-slab (8*16384 B)
    asm volatile("s_waitcnt vmcnt(0)" ::: "memory");    // drain both h stores
    if (lane == 0)
      __hip_atomic_store(myflag, l + 1, __ATOMIC_RELAXED, __HIP_MEMORY_SCOPE_AGENT);
  }
}

// ---------------- launch ----------------
extern "C" void kernel_launch(void* const* d_in, const int* in_sizes, int n_in,
                              void* d_out, int out_size, void* d_ws, size_t ws_size,
                              hipStream_t stream)
{
  (void)in_sizes; (void)n_in; (void)out_size; (void)ws_size;
  const float* in_feats = (const float*)d_in[0];
  const int*   e_src    = (const int*)d_in[1];
  const int*   e_dst    = (const int*)d_in[2];
  const int*   seq      = (const int*)d_in[3];
  const float* W_conv   = (const float*)d_in[4];
  const float* b_conv   = (const float*)d_in[5];
  const float* W_ff1    = (const float*)d_in[6];
  const float* b_ff1    = (const float*)d_in[7];
  const float* W_ih     = (const float*)d_in[8];
  const float* W_hh     = (const float*)d_in[9];
  const float* b_ih     = (const float*)d_in[10];
  const float* b_hh     = (const float*)d_in[11];
  const float* W_ff2    = (const float*)d_in[12];
  const float* b_ff2    = (const float*)d_in[13];

  uint8_t* ws = (uint8_t*)d_ws;
  int*  deg     = (int*) (ws + 0);
  int*  cursor  = (int*) (ws + 262144u);
  int*  roff    = (int*) (ws + 524288u);
  bf16* WcT     = (bf16*)(ws + 1048576u);
  bf16* Wf1T    = (bf16*)(ws + 1572864u);
  bf16* Wf2T    = (bf16*)(ws + 2097152u);
  bf16* WihB    = (bf16*)(ws + 2621440u);
  bf16* WhhB    = (bf16*)(ws + 4194304u);
  int*  csr     = (int*) (ws + 6291456u);
  int*  flags   = (int*) (ws + 10485760u);     // 8 chains x 16 producers x 128B = 16KB
  int*  partial = (int*) (ws + 10616832u);     // 64 ints
  int*  sbase   = (int*) (ws + 10620928u);     // 65 ints
  bf16* med2    = (bf16*)(ws + 16777216u);     // 67MB; reused as ys2 after gi GEMM
  uint8_t* ys2  = (uint8_t*)med2;              // [l][chain][k-chunk][gl][..] bf16 = 64MB
  bf16* gib     = (bf16*)(ws + 83886080u);     // 201MB; aggb/med1/featsb live here pre-gi
  bf16* aggb    = (bf16*)(ws + 83886080u);
  bf16* med1    = (bf16*)(ws + 150994944u);    // also featsb (dead before med1 written)
  bf16* featsb  = (bf16*)(ws + 150994944u);

  hipMemsetAsync(deg,   0, NN * 4,          stream);
  hipMemsetAsync(flags, 0, 8 * 16 * 32 * 4, stream);

  k_prep <<<3072, 256, 0, stream>>>(W_conv, W_ff1, W_ff2, W_ih, W_hh, WcT, Wf1T, Wf2T, WihB, WhhB);
  k_cast <<<NN * DD / 1024, 256, 0, stream>>>(in_feats, featsb);
  k_deg  <<<EE / 256, 256, 0, stream>>>(e_dst, deg);
  k_scan1<<<64, 1024, 0, stream>>>(deg, roff, partial);
  k_scan2<<<1, 64, 0, stream>>>(partial, sbase);
  k_scan3<<<64, 1024, 0, stream>>>(sbase, roff, cursor);
  k_fill <<<EE / 256, 256, 0, stream>>>(e_src, e_dst, cursor, csr);
  k_agg  <<<NN, 128, 0, stream>>>(featsb, csr, roff, aggb);

  dim3 g512(4, 512), g1536(12, 512);
  k_gemm<false, false><<<g512,  256, 0, stream>>>(aggb, WcT,  b_conv, nullptr, med1, 512);
  k_gemm<false, true ><<<g512,  256, 0, stream>>>(med1, Wf1T, b_ff1,  nullptr, med2, 512);
  k_gemm<true,  false><<<g1536, 256, 0, stream>>>(med2, WihB, b_ih,   seq,     gib,  1536);

  k_gru13<<<128, 64, 0, stream>>>(WhhB, b_hh, gib, ys2, flags);

  k_gemm_ys<<<g512, 256, 0, stream>>>(ys2, Wf2T, b_ff2, seq, (float*)d_out);
}